// Round 8
// baseline (302.873 us; speedup 1.0000x reference)
//
#include <hip/hip_runtime.h>
#include <hip/hip_bf16.h>

// Problem constants (match reference)
constexpr int NE  = 8;
constexpr int T   = 2048;
constexpr int IN  = 2048;
constexpr int OUT = 2048;
constexpr int GS  = 64;
constexpr int G   = IN / GS;

// Stage-2 GEMM tiling (m97-style: global_load_lds + 2-barrier K-loop)
constexpr int BM = 128;
constexpr int BN = 128;
constexpr int BK = 64;

using short8  = __attribute__((ext_vector_type(8))) short;
using floatx4 = __attribute__((ext_vector_type(4))) float;

// async global->LDS, 16B per lane (LDS dest = uniform base + lane*16)
__device__ __forceinline__ void gld_lds16(const void* g, void* l) {
    __builtin_amdgcn_global_load_lds(
        (const __attribute__((address_space(1))) unsigned int*)g,
        (__attribute__((address_space(3))) unsigned int*)l, 16, 0, 0);
}

// ---- stage 0: x fp32 -> bf16 ----
__global__ __launch_bounds__(256)
void cvt_x_bf16(const float* __restrict__ x, __hip_bfloat16* __restrict__ xb) {
    const int i = (blockIdx.x * 256 + threadIdx.x) * 4;
    const float4 v = *(const float4*)(x + i);
    union { unsigned long long u; __hip_bfloat162 h2[2]; } p;
    p.h2[0] = __float22bfloat162_rn(float2{v.x, v.y});
    p.h2[1] = __float22bfloat162_rn(float2{v.z, v.w});
    *(unsigned long long*)(xb + i) = p.u;
}

// ---- stage 1: dequant + transpose via LDS ----
// qweight[E][IN][OUT] (int32 codes, n-contig) -> wt[E][OUT][IN] bf16 (k-contig).
// Block = (n-chunk 64, k-chunk 256, e).
// Phase 1 reads: lane-across-n, 256 B/inst fully coalesced (R7's k-gather reads
// were 8x8KB-strided -> latency-bound at VGPR 28). Phase 2 stores: full-line
// (8 rows x 128 B per wave inst, no RFO). LDS b128 row-stride 132 dw == 4 mod 32
// -> every 8-lane phase hits all 32 banks exactly once (conflict-free).
constexpr int DQK = 256;               // k per block (4 quant groups)
constexpr int DQN = 64;                // n per block
constexpr int LDQ = DQK + 8;           // bf16 elems; 132 dwords per row

__global__ __launch_bounds__(256)
void dequant_wt(const int* __restrict__ qw, const float* __restrict__ snz,
                __hip_bfloat16* __restrict__ wt) {
    const int tid = threadIdx.x;
    const int e  = blockIdx.z;
    const int kc = blockIdx.y * DQK;
    const int n0 = blockIdx.x * DQN;

    __shared__ __hip_bfloat16 Bs[DQN][LDQ];

    // phase 1: thread = (n = tid&63, quant-group kg = tid>>6); 64 coalesced loads
    const int n  = tid & 63;
    const int kg = tid >> 6;                   // 0..3, k in [kg*64, kg*64+64)
    {
        const float2 sz = ((const float2*)snz)[(size_t)e * G * OUT +
                                               (size_t)((kc >> 6) + kg) * OUT + n0 + n];
        const float s = sz.x;
        const float c = sz.y - 8.0f * s;       // (q-8)*s+z == q*s+c
        const int* qp = qw + (size_t)e * IN * OUT + (size_t)(kc + kg * 64) * OUT + n0 + n;
#pragma unroll
        for (int j = 0; j < 8; ++j) {
            int q[8];
#pragma unroll
            for (int jj = 0; jj < 8; ++jj)
                q[jj] = qp[(size_t)(j * 8 + jj) * OUT];   // 256 B/inst across lanes
            union { short8 v; __hip_bfloat162 h2[4]; } pb;
#pragma unroll
            for (int jj = 0; jj < 4; ++jj) {
                const float f0 = (float)q[2 * jj]     * s + c;
                const float f1 = (float)q[2 * jj + 1] * s + c;
                pb.h2[jj] = __float22bfloat162_rn(float2{f0, f1});
            }
            *(short8*)&Bs[n][kg * 64 + j * 8] = pb.v;     // conflict-free b128
        }
    }

    __syncthreads();

    // phase 2: thread = (n2 = tid>>3, ko = (tid&7)*8); 8 b128 reads + stores
    const int n2 = tid >> 3;                   // 0..31
    const int ko = (tid & 7) * 8;
    __hip_bfloat16* wp = wt + (size_t)e * OUT * IN + (size_t)(n0 + n2) * IN + kc + ko;
#pragma unroll
    for (int it = 0; it < 8; ++it) {
        const int na = (it & 1) * 32;          // n offset
        const int kb = (it >> 1) * 64;         // k offset
        const short8 v = *(const short8*)&Bs[n2 + na][ko + kb];
        *(short8*)(wp + (size_t)na * IN + kb) = v;   // wave: 8 rows x 128 B, full lines
    }
}

// ---- stage 2: grouped GEMM, m97 structure, 128x128 tile ----
__global__ __launch_bounds__(256, 2)
void hqq_gemm(const __hip_bfloat16* __restrict__ xb,
              const __hip_bfloat16* __restrict__ wt,   // [E][OUT][IN] bf16
              const int* __restrict__ tpe,
              float* __restrict__ out) {
    const int tid = threadIdx.x;
    const int e   = blockIdx.z;
    const int tm  = blockIdx.y;
    const int n0  = blockIdx.x * BN;

    int b0 = 0;
    for (int i = 0; i < NE; ++i) {
        int c = tpe[i];
        if (i < e) b0 += c;
    }
    const int b1 = b0 + tpe[e];
    const int row0 = b0 + tm * BM;
    if (row0 >= b1) return;

    __shared__ __hip_bfloat16 As[BM * BK];   // [m][k]
    __shared__ __hip_bfloat16 Bs[BN * BK];   // [n][k]

    const int sm = tid >> 3;          // 0..31
    const int sk = (tid & 7) * 8;

    const int lane = tid & 63;
    const int wid  = tid >> 6;
    const int wm = (wid >> 1) * 64;   // 2x2 waves of 64x64
    const int wn = (wid & 1) * 64;
    const int lm = lane & 15;
    const int lk = (lane >> 4) * 8;
    const int lq = (lane >> 4) * 4;

    floatx4 acc[4][4];
#pragma unroll
    for (int i = 0; i < 4; ++i)
#pragma unroll
        for (int j = 0; j < 4; ++j)
            acc[i][j] = (floatx4){0.f, 0.f, 0.f, 0.f};

    int arow[4];
#pragma unroll
    for (int I = 0; I < 4; ++I) {
        int r = row0 + sm + 32 * I;
        arow[I] = r < T ? r : (T - 1);   // clamp; garbage rows never stored
    }
    const __hip_bfloat16* wbase = wt + (size_t)e * OUT * IN + (size_t)(n0 + sm) * IN;

    for (int k0 = 0; k0 < IN; k0 += BK) {
        // 4 A-issues + 4 B-issues, 16 B/lane each, drained at the barrier
#pragma unroll
        for (int I = 0; I < 4; ++I)
            gld_lds16(xb + (size_t)arow[I] * IN + k0 + sk,
                      &As[(sm + 32 * I) * BK + sk]);
#pragma unroll
        for (int I = 0; I < 4; ++I)
            gld_lds16(wbase + (size_t)(32 * I) * IN + k0 + sk,
                      &Bs[(sm + 32 * I) * BK + sk]);

        __syncthreads();

#pragma unroll
        for (int ks = 0; ks < BK; ks += 32) {
            short8 af[4], bfr[4];
#pragma unroll
            for (int i = 0; i < 4; ++i)
                af[i] = *(const short8*)&As[(wm + i * 16 + lm) * BK + ks + lk];
#pragma unroll
            for (int j = 0; j < 4; ++j)
                bfr[j] = *(const short8*)&Bs[(wn + j * 16 + lm) * BK + ks + lk];
#pragma unroll
            for (int i = 0; i < 4; ++i)
#pragma unroll
                for (int j = 0; j < 4; ++j)
                    acc[i][j] = __builtin_amdgcn_mfma_f32_16x16x32_bf16(
                        af[i], bfr[j], acc[i][j], 0, 0, 0);
        }

        __syncthreads();
    }

    // epilogue: exactly-once plain stores (C/D: col=lane&15, row=quad*4+reg)
#pragma unroll
    for (int i = 0; i < 4; ++i) {
#pragma unroll
        for (int r = 0; r < 4; ++r) {
            const int row = row0 + wm + i * 16 + lq + r;
            if (row < b1) {
                float* op = out + (size_t)row * OUT + n0 + wn + lm;
#pragma unroll
                for (int j = 0; j < 4; ++j)
                    op[j * 16] = acc[i][j][r];
            }
        }
    }
}

extern "C" void kernel_launch(void* const* d_in, const int* in_sizes, int n_in,
                              void* d_out, int out_size, void* d_ws, size_t ws_size,
                              hipStream_t stream) {
    const float* x   = (const float*)d_in[0];
    const int*   qw  = (const int*)d_in[1];
    const float* snz = (const float*)d_in[2];
    const int*   tpe = (const int*)d_in[3];
    float* out = (float*)d_out;

    const size_t xb_bytes = (size_t)T * IN * sizeof(__hip_bfloat16);   // 8.4 MB
    __hip_bfloat16* xb = (__hip_bfloat16*)d_ws;
    __hip_bfloat16* wt = (__hip_bfloat16*)((char*)d_ws + xb_bytes);    // 67.1 MB

    cvt_x_bf16<<<(T * IN) / (256 * 4), 256, 0, stream>>>(x, xb);

    // 32 n-chunks x 8 k-chunks x 8 experts = 2048 blocks
    dequant_wt<<<dim3(OUT / DQN, IN / DQK, NE), 256, 0, stream>>>(qw, snz, wt);

    hqq_gemm<<<dim3(OUT / BN, T / BM, NE), 256, 0, stream>>>(xb, wt, tpe, out);
}